// Round 1
// baseline (236.704 us; speedup 1.0000x reference)
//
#include <hip/hip_runtime.h>

#define HID   768
#define SEQ   128
#define NROWS 512
#define PAIRS_PER_MAT (NROWS * (HID/2))

typedef __bf16 bf16x8 __attribute__((ext_vector_type(8)));
typedef float  floatx4 __attribute__((ext_vector_type(4)));

__device__ __forceinline__ unsigned short f2bf(float x) {   // RNE f32->bf16, finite only
    unsigned u = __builtin_bit_cast(unsigned, x);
    unsigned r = u + 0x7FFFu + ((u >> 16) & 1u);
    return (unsigned short)(r >> 16);
}

// ---- kernel 1: rotary (f32 in) -> bf16 rot buffer [2][512][768]
// one even/odd pair per thread; no redundant sincos (vs fused-in-gemm version).
__global__ __launch_bounds__(256) void rotary_kernel(
    const float* __restrict__ review,
    const float* __restrict__ reply,
    unsigned short* __restrict__ rot)
{
    int p   = blockIdx.x * 256 + threadIdx.x;
    int mat = (p >= PAIRS_PER_MAT) ? 1 : 0;
    int rem = p - mat * PAIRS_PER_MAT;
    int row = rem / (HID / 2);
    int i   = rem - row * (HID / 2);
    int s   = row & 127;

    const float* src = (mat ? reply : review) + row * HID + 2 * i;
    float2 x = *reinterpret_cast<const float2*>(src);

    // inv_freq = 10000^(-i/384); log2(10000) = 13.287712379549449
    float inv = exp2f((float)i * (-13.287712379549449f / 384.0f));
    float sn, c;
    __sincosf((float)s * inv, &sn, &c);

    float oe = x.x * c - x.y * sn;
    float oo = x.y * c + x.x * sn;
    unsigned pk = (unsigned)f2bf(oe) | ((unsigned)f2bf(oo) << 16);
    *reinterpret_cast<unsigned*>(rot + (size_t)mat * (NROWS * HID) + row * HID + 2 * i) = pk;
}

// ---- kernel 2: proj[mat][row][o] = sum_h rot[mat][row][h] * W[o][mat*768+h]
// 64x64 tile, BK=192 -> 4 k-chunks, register prefetch of next chunk during MFMA.
// LDS rows padded to 200 elems (400 B stride = 4-bank rotation; <=2-way, free).
__global__ __launch_bounds__(256) void gemm_kernel(
    const unsigned short* __restrict__ rot,
    const float* __restrict__ W,              // [768][1536] f32
    float* __restrict__ proj)                 // [2][512][768] f32
{
    __shared__ __align__(16) unsigned short As[64 * 200];
    __shared__ __align__(16) unsigned short Bs[64 * 200];

    const int tid  = threadIdx.x;
    const int lane = tid & 63;
    const int wave = tid >> 6;
    const int mat  = blockIdx.z;
    const int row0 = blockIdx.y * 64;
    const int col0 = blockIdx.x * 64;
    const int q    = lane >> 4;
    const int r16  = lane & 15;

    const int srow = tid >> 2;           // 0..63 : staged row (A-row / B-col o)
    const int sko  = (tid & 3) * 48;     // 0,48,96,144 : k-offset within chunk

    const unsigned short* Arow = rot + (size_t)mat * (NROWS * HID)
                                     + (size_t)(row0 + srow) * HID + sko;
    const float* Wrow = W + (size_t)(col0 + srow) * (2 * HID) + mat * HID + sko;

    floatx4 acc[4];
#pragma unroll
    for (int c = 0; c < 4; ++c) acc[c] = (floatx4)0.0f;

    // prologue: chunk 0 into registers (6 uint4 A = 48 bf16, 12 float4 W = 48 f32)
    uint4   aR[6];
    floatx4 wR[12];
#pragma unroll
    for (int j = 0; j < 6; ++j)  aR[j] = *reinterpret_cast<const uint4*>(Arow + j * 8);
#pragma unroll
    for (int j = 0; j < 12; ++j) wR[j] = *reinterpret_cast<const floatx4*>(Wrow + j * 4);

    for (int ch = 0; ch < 4; ++ch) {
        // stage registers -> LDS (A is bf16 copy; W packed f32->bf16)
#pragma unroll
        for (int j = 0; j < 6; ++j)
            *reinterpret_cast<uint4*>(&As[srow * 200 + sko + j * 8]) = aR[j];
#pragma unroll
        for (int j = 0; j < 6; ++j) {
            floatx4 w0 = wR[2 * j], w1 = wR[2 * j + 1];
            uint4 pk;
            pk.x = (unsigned)f2bf(w0.x) | ((unsigned)f2bf(w0.y) << 16);
            pk.y = (unsigned)f2bf(w0.z) | ((unsigned)f2bf(w0.w) << 16);
            pk.z = (unsigned)f2bf(w1.x) | ((unsigned)f2bf(w1.y) << 16);
            pk.w = (unsigned)f2bf(w1.z) | ((unsigned)f2bf(w1.w) << 16);
            *reinterpret_cast<uint4*>(&Bs[srow * 200 + sko + j * 8]) = pk;
        }
        __syncthreads();

        // prefetch next chunk while MFMAs consume LDS
        if (ch < 3) {
#pragma unroll
            for (int j = 0; j < 6; ++j)
                aR[j] = *reinterpret_cast<const uint4*>(Arow + (ch + 1) * 192 + j * 8);
#pragma unroll
            for (int j = 0; j < 12; ++j)
                wR[j] = *reinterpret_cast<const floatx4*>(Wrow + (ch + 1) * 192 + j * 4);
        }

#pragma unroll
        for (int kk = 0; kk < 6; ++kk) {
            bf16x8 af = *reinterpret_cast<const bf16x8*>(&As[(wave * 16 + r16) * 200 + kk * 32 + q * 8]);
#pragma unroll
            for (int c = 0; c < 4; ++c) {
                bf16x8 bf = *reinterpret_cast<const bf16x8*>(&Bs[(c * 16 + r16) * 200 + kk * 32 + q * 8]);
                acc[c] = __builtin_amdgcn_mfma_f32_16x16x32_bf16(af, bf, acc[c], 0, 0, 0);
            }
        }
        __syncthreads();
    }

    // C/D layout: col = lane&15, row = (lane>>4)*4 + reg  [verified mapping]
    float* pbase = proj + (size_t)mat * (NROWS * HID);
#pragma unroll
    for (int c = 0; c < 4; ++c) {
        int col = col0 + c * 16 + r16;
#pragma unroll
        for (int rg = 0; rg < 4; ++rg) {
            int row = row0 + wave * 16 + q * 4 + rg;
            pbase[row * HID + col] = acc[c][rg];
        }
    }
}

// ---- kernel 3: out[b,n,m,o] = relu(pr[b,n,o] + pp[b,m,o] + bias[o]) -> f32
// grid (512, 8): block = one (b,n) x 16 m-rows.
// Linear float4 stream: out float4 index == pp float4 index == idx; prb index = idx%192.
// Stores are NONTEMPORAL: the 201 MB out stream is write-once, never re-read;
// keeping it out of L2 preserves L2 for the pp tiles shared by 128 blocks each.
__global__ __launch_bounds__(256) void bcast_kernel(
    const float* __restrict__ proj,
    const float* __restrict__ bias,
    float* __restrict__ out)
{
    const int bn    = blockIdx.x;          // b*128 + n
    const int chunk = blockIdx.y;          // 0..7 : 16 m-rows each
    const int b     = bn >> 7;

    __shared__ __align__(16) float prb[HID];
    const float* pr = proj + (size_t)bn * HID;
    for (int o = threadIdx.x; o < HID; o += 256)
        prb[o] = pr[o] + bias[o];
    __syncthreads();

    const floatx4* pp4  = reinterpret_cast<const floatx4*>(
        proj + (size_t)(NROWS + b * SEQ + chunk * 16) * HID);
    const floatx4* prb4 = reinterpret_cast<const floatx4*>(prb);
    floatx4* ob4 = reinterpret_cast<floatx4*>(
        out + (size_t)bn * (SEQ * HID) + (size_t)chunk * 16 * HID);

#pragma unroll
    for (int it = 0; it < 12; ++it) {
        int idx = it * 256 + threadIdx.x;      // 0..3071 : linear float4 index
        floatx4 p = pp4[idx];
        floatx4 a = prb4[idx % 192];           // 192 = HID/4
        floatx4 r;
        r.x = fmaxf(a.x + p.x, 0.0f);
        r.y = fmaxf(a.y + p.y, 0.0f);
        r.z = fmaxf(a.z + p.z, 0.0f);
        r.w = fmaxf(a.w + p.w, 0.0f);
        __builtin_nontemporal_store(r, &ob4[idx]);
    }
}

extern "C" void kernel_launch(void* const* d_in, const int* in_sizes, int n_in,
                              void* d_out, int out_size, void* d_ws, size_t ws_size,
                              hipStream_t stream) {
    const float* review = (const float*)d_in[0];
    const float* reply  = (const float*)d_in[1];
    const float* W      = (const float*)d_in[2];
    const float* bias   = (const float*)d_in[3];
    float* out = (float*)d_out;

    unsigned short* rot = (unsigned short*)d_ws;                       // 1.5 MB bf16
    float* proj = (float*)((char*)d_ws + (size_t)2 * NROWS * HID * 2); // 3 MB f32

    rotary_kernel<<<PAIRS_PER_MAT * 2 / 256, 256, 0, stream>>>(review, reply, rot);
    dim3 g2(HID / 64, NROWS / 64, 2);   // 12 x 8 x 2 = 192 blocks
    gemm_kernel<<<g2, 256, 0, stream>>>(rot, W, proj);
    dim3 g3(NROWS, 8);                  // 4096 blocks
    bcast_kernel<<<g3, 256, 0, stream>>>(proj, bias, out);
}

// Round 2
// 226.525 us; speedup vs baseline: 1.0449x; 1.0449x over previous
//
#include <hip/hip_runtime.h>

#define HID   768
#define SEQ   128
#define NROWS 512
#define PAIRS_PER_MAT (NROWS * (HID/2))

typedef __bf16 bf16x8 __attribute__((ext_vector_type(8)));
typedef float  floatx4 __attribute__((ext_vector_type(4)));

__device__ __forceinline__ unsigned short f2bf(float x) {   // RNE f32->bf16, finite only
    unsigned u = __builtin_bit_cast(unsigned, x);
    unsigned r = u + 0x7FFFu + ((u >> 16) & 1u);
    return (unsigned short)(r >> 16);
}

// ---- kernel 1: rotary (f32 in) -> bf16 rot buffer [2][512][768]
// one even/odd pair per thread; no redundant sincos (vs fused-in-gemm version).
__global__ __launch_bounds__(256) void rotary_kernel(
    const float* __restrict__ review,
    const float* __restrict__ reply,
    unsigned short* __restrict__ rot)
{
    int p   = blockIdx.x * 256 + threadIdx.x;
    int mat = (p >= PAIRS_PER_MAT) ? 1 : 0;
    int rem = p - mat * PAIRS_PER_MAT;
    int row = rem / (HID / 2);
    int i   = rem - row * (HID / 2);
    int s   = row & 127;

    const float* src = (mat ? reply : review) + row * HID + 2 * i;
    float2 x = *reinterpret_cast<const float2*>(src);

    // inv_freq = 10000^(-i/384); log2(10000) = 13.287712379549449
    float inv = exp2f((float)i * (-13.287712379549449f / 384.0f));
    float sn, c;
    __sincosf((float)s * inv, &sn, &c);

    float oe = x.x * c - x.y * sn;
    float oo = x.y * c + x.x * sn;
    unsigned pk = (unsigned)f2bf(oe) | ((unsigned)f2bf(oo) << 16);
    *reinterpret_cast<unsigned*>(rot + (size_t)mat * (NROWS * HID) + row * HID + 2 * i) = pk;
}

// ---- kernel 2: proj[mat][row][o] = sum_h rot[mat][row][h] * W[o][mat*768+h]
// 64x64 tile, BK=192 -> 4 k-chunks, register prefetch of next chunk during MFMA.
// LDS rows padded to 200 elems (400 B stride = 4-bank rotation; <=2-way, free).
__global__ __launch_bounds__(256) void gemm_kernel(
    const unsigned short* __restrict__ rot,
    const float* __restrict__ W,              // [768][1536] f32
    float* __restrict__ proj)                 // [2][512][768] f32
{
    __shared__ __align__(16) unsigned short As[64 * 200];
    __shared__ __align__(16) unsigned short Bs[64 * 200];

    const int tid  = threadIdx.x;
    const int lane = tid & 63;
    const int wave = tid >> 6;
    const int mat  = blockIdx.z;
    const int row0 = blockIdx.y * 64;
    const int col0 = blockIdx.x * 64;
    const int q    = lane >> 4;
    const int r16  = lane & 15;

    const int srow = tid >> 2;           // 0..63 : staged row (A-row / B-col o)
    const int sko  = (tid & 3) * 48;     // 0,48,96,144 : k-offset within chunk

    const unsigned short* Arow = rot + (size_t)mat * (NROWS * HID)
                                     + (size_t)(row0 + srow) * HID + sko;
    const float* Wrow = W + (size_t)(col0 + srow) * (2 * HID) + mat * HID + sko;

    floatx4 acc[4];
#pragma unroll
    for (int c = 0; c < 4; ++c) acc[c] = (floatx4)0.0f;

    // prologue: chunk 0 into registers (6 uint4 A = 48 bf16, 12 float4 W = 48 f32)
    uint4   aR[6];
    floatx4 wR[12];
#pragma unroll
    for (int j = 0; j < 6; ++j)  aR[j] = *reinterpret_cast<const uint4*>(Arow + j * 8);
#pragma unroll
    for (int j = 0; j < 12; ++j) wR[j] = *reinterpret_cast<const floatx4*>(Wrow + j * 4);

    for (int ch = 0; ch < 4; ++ch) {
        // stage registers -> LDS (A is bf16 copy; W packed f32->bf16)
#pragma unroll
        for (int j = 0; j < 6; ++j)
            *reinterpret_cast<uint4*>(&As[srow * 200 + sko + j * 8]) = aR[j];
#pragma unroll
        for (int j = 0; j < 6; ++j) {
            floatx4 w0 = wR[2 * j], w1 = wR[2 * j + 1];
            uint4 pk;
            pk.x = (unsigned)f2bf(w0.x) | ((unsigned)f2bf(w0.y) << 16);
            pk.y = (unsigned)f2bf(w0.z) | ((unsigned)f2bf(w0.w) << 16);
            pk.z = (unsigned)f2bf(w1.x) | ((unsigned)f2bf(w1.y) << 16);
            pk.w = (unsigned)f2bf(w1.z) | ((unsigned)f2bf(w1.w) << 16);
            *reinterpret_cast<uint4*>(&Bs[srow * 200 + sko + j * 8]) = pk;
        }
        __syncthreads();

        // prefetch next chunk while MFMAs consume LDS
        if (ch < 3) {
#pragma unroll
            for (int j = 0; j < 6; ++j)
                aR[j] = *reinterpret_cast<const uint4*>(Arow + (ch + 1) * 192 + j * 8);
#pragma unroll
            for (int j = 0; j < 12; ++j)
                wR[j] = *reinterpret_cast<const floatx4*>(Wrow + (ch + 1) * 192 + j * 4);
        }

#pragma unroll
        for (int kk = 0; kk < 6; ++kk) {
            bf16x8 af = *reinterpret_cast<const bf16x8*>(&As[(wave * 16 + r16) * 200 + kk * 32 + q * 8]);
#pragma unroll
            for (int c = 0; c < 4; ++c) {
                bf16x8 bf = *reinterpret_cast<const bf16x8*>(&Bs[(c * 16 + r16) * 200 + kk * 32 + q * 8]);
                acc[c] = __builtin_amdgcn_mfma_f32_16x16x32_bf16(af, bf, acc[c], 0, 0, 0);
            }
        }
        __syncthreads();
    }

    // C/D layout: col = lane&15, row = (lane>>4)*4 + reg  [verified mapping]
    float* pbase = proj + (size_t)mat * (NROWS * HID);
#pragma unroll
    for (int c = 0; c < 4; ++c) {
        int col = col0 + c * 16 + r16;
#pragma unroll
        for (int rg = 0; rg < 4; ++rg) {
            int row = row0 + wave * 16 + q * 4 + rg;
            pbase[row * HID + col] = acc[c][rg];
        }
    }
}

// ---- kernel 3: out[b,n,m,o] = relu(pr[b,n,o] + pp[b,m,o] + bias[o]) -> f32
// One block per (b,n). Block writes a CONTIGUOUS 384 KB span (128 m-rows x 768 o).
// Linear float4 stream: out4[idx] = relu(a[idx%192] + pp4[idx]), idx = it*256+tid.
// Since idx%192 has period 3 in `it`, each thread needs only THREE pr+bias values:
// they live in registers -> no LDS, no barrier, no per-iter modulo. Plain cached
// stores (the rocclr fill kernel proves 6.26 TB/s with this store path).
__global__ __launch_bounds__(256) void bcast_kernel(
    const float* __restrict__ proj,
    const float* __restrict__ bias,
    float* __restrict__ out)
{
    const int bn  = blockIdx.x;            // b*128 + n
    const int b   = bn >> 7;
    const int tid = threadIdx.x;

    const floatx4* pr4   = reinterpret_cast<const floatx4*>(proj + (size_t)bn * HID);
    const floatx4* bias4 = reinterpret_cast<const floatx4*>(bias);
    const floatx4* pp4   = reinterpret_cast<const floatx4*>(
        proj + (size_t)(NROWS + b * SEQ) * HID);
    floatx4* out4 = reinterpret_cast<floatx4*>(out + (size_t)bn * (SEQ * HID));

    // the three o-positions this thread ever touches (o = idx % 192)
    int o0 = (tid < 192) ? tid : tid - 192;
    int o1 = o0 + 64;  if (o1 >= 192) o1 -= 192;
    int o2 = o1 + 64;  if (o2 >= 192) o2 -= 192;

    floatx4 a0 = pr4[o0] + bias4[o0];
    floatx4 a1 = pr4[o1] + bias4[o1];
    floatx4 a2 = pr4[o2] + bias4[o2];

    // 96 iterations of 256 float4 = 24576 float4 = 128 rows x 192; groups of 3.
#pragma unroll 2
    for (int g = 0; g < 32; ++g) {
        int base = g * 768 + tid;
        {
            floatx4 p = pp4[base];
            floatx4 r;
            r.x = fmaxf(a0.x + p.x, 0.0f); r.y = fmaxf(a0.y + p.y, 0.0f);
            r.z = fmaxf(a0.z + p.z, 0.0f); r.w = fmaxf(a0.w + p.w, 0.0f);
            out4[base] = r;
        }
        {
            floatx4 p = pp4[base + 256];
            floatx4 r;
            r.x = fmaxf(a1.x + p.x, 0.0f); r.y = fmaxf(a1.y + p.y, 0.0f);
            r.z = fmaxf(a1.z + p.z, 0.0f); r.w = fmaxf(a1.w + p.w, 0.0f);
            out4[base + 256] = r;
        }
        {
            floatx4 p = pp4[base + 512];
            floatx4 r;
            r.x = fmaxf(a2.x + p.x, 0.0f); r.y = fmaxf(a2.y + p.y, 0.0f);
            r.z = fmaxf(a2.z + p.z, 0.0f); r.w = fmaxf(a2.w + p.w, 0.0f);
            out4[base + 512] = r;
        }
    }
}

extern "C" void kernel_launch(void* const* d_in, const int* in_sizes, int n_in,
                              void* d_out, int out_size, void* d_ws, size_t ws_size,
                              hipStream_t stream) {
    const float* review = (const float*)d_in[0];
    const float* reply  = (const float*)d_in[1];
    const float* W      = (const float*)d_in[2];
    const float* bias   = (const float*)d_in[3];
    float* out = (float*)d_out;

    unsigned short* rot = (unsigned short*)d_ws;                       // 1.5 MB bf16
    float* proj = (float*)((char*)d_ws + (size_t)2 * NROWS * HID * 2); // 3 MB f32

    rotary_kernel<<<PAIRS_PER_MAT * 2 / 256, 256, 0, stream>>>(review, reply, rot);
    dim3 g2(HID / 64, NROWS / 64, 2);   // 12 x 8 x 2 = 192 blocks
    gemm_kernel<<<g2, 256, 0, stream>>>(rot, W, proj);
    bcast_kernel<<<NROWS, 256, 0, stream>>>(proj, bias, out);          // 512 blocks
}